// Round 3
// baseline (142.048 us; speedup 1.0000x reference)
//
#include <hip/hip_runtime.h>
#include <hip/hip_bf16.h>

typedef short bf16x8 __attribute__((ext_vector_type(8)));
typedef float f32x4  __attribute__((ext_vector_type(4)));

#define ZD      128      // feature dim
#define BT      128      // block tile
#define D2_CUT  60.0f    // exact-path cutoff: exp(-30)~9e-14
#define D2_TRIG 62.0f    // conservative trigger (margin > any bf16 dot err)

__device__ __forceinline__ unsigned short f2bf(float x) {
    unsigned u = __float_as_uint(x);
    u = (u + 0x7FFFu + ((u >> 16) & 1u)) >> 16;
    return (unsigned short)u;
}

// ---------------------------------------------------------------------------
// Kernel A: ||z_i||^2, per-64-row min, z->bf16, per-block class counts
// (plain stores -> no zero-init, no atomics). Block 0 zeroes acc + done.
// ---------------------------------------------------------------------------
__global__ __launch_bounds__(256) void dep_prep(
    const float* __restrict__ z, const int* __restrict__ s,
    float* __restrict__ sq, float* __restrict__ sqmin,
    unsigned short* __restrict__ zb, int* __restrict__ counts4,
    float* __restrict__ acc, unsigned int* __restrict__ done)
{
    __shared__ float part[64][33];
    const int tid  = threadIdx.x;
    const int wave = tid >> 6, lane = tid & 63;
    const int half = lane >> 5, c = lane & 31;
    const int r0   = blockIdx.x * 64;

    if (blockIdx.x == 0 && tid == 192) { *acc = 0.0f; *done = 0u; }

    if (wave == 0) {
        int sv = s[r0 + lane];
        #pragma unroll
        for (int cl = 0; cl < 4; ++cl) {
            unsigned long long m = __ballot(sv == cl);
            if (lane == 0) counts4[blockIdx.x * 4 + cl] = __popcll(m);
        }
    }

    #pragma unroll
    for (int i = 0; i < 8; ++i) {
        const int rloc = wave * 16 + i * 2 + half;
        const int r    = r0 + rloc;
        float4 v = ((const float4*)z)[r * 32 + c];
        ushort4 u;
        u.x = f2bf(v.x); u.y = f2bf(v.y); u.z = f2bf(v.z); u.w = f2bf(v.w);
        ((ushort4*)zb)[r * 32 + c] = u;
        part[rloc][c] = v.x*v.x + v.y*v.y + v.z*v.z + v.w*v.w;
    }
    __syncthreads();

    if (wave == 0) {
        float sum = 0.f;
        #pragma unroll
        for (int k = 0; k < 32; ++k) sum += part[lane][k];
        sq[r0 + lane] = sum;
        float mn = sum;
        #pragma unroll
        for (int off = 1; off < 64; off <<= 1)
            mn = fminf(mn, __shfl_xor(mn, off, 64));
        if (lane == 0) sqmin[blockIdx.x] = mn;
    }
}

// ---------------------------------------------------------------------------
// Kernel B: one block per 128x128 upper-triangle tile (2080 blocks).
// B panel staged in 32KB LDS (XOR-swizzled, conflict-free); A fragments
// loaded straight from global (16x64B lines per instr, L1-shared between
// the two waves of each row-half) with kc+1 double-buffered prefetch.
// Epilogue: conservative d2 bound; exact path only when it fires.
// Last block (done counter) finalizes: diagonal analytic + scaling -> out.
// ---------------------------------------------------------------------------
__global__ __launch_bounds__(256, 3) void dep_pair(
    const unsigned short* __restrict__ zb, const float* __restrict__ sq,
    const float* __restrict__ sqmin, const int* __restrict__ s,
    const int* __restrict__ counts4, int nPrep,
    float* __restrict__ acc, unsigned int* __restrict__ done,
    const float* __restrict__ norm, float* __restrict__ out,
    int T, int N, float invN)
{
    __shared__ unsigned short Bpan[BT * ZD];   // 32KB

    const int tid = threadIdx.x;

    // block-uniform triangle map t -> (ti <= tj)
    const int t = blockIdx.x;
    #define TRI_BASE(x) ((x) * T - ((x) * ((x) - 1)) / 2)
    double disc = (2.0 * T + 1.0) * (2.0 * T + 1.0) - 8.0 * (double)t;
    int ti = (int)((2.0 * T + 1.0 - sqrt(disc)) * 0.5);
    if (ti < 0) ti = 0;
    if (ti > T - 1) ti = T - 1;
    while (ti + 1 < T && TRI_BASE(ti + 1) <= t) ++ti;
    while (ti > 0 && TRI_BASE(ti) > t) --ti;
    const int tj = ti + (t - TRI_BASE(ti));
    #undef TRI_BASE

    const int i0 = ti * BT, j0 = tj * BT;
    const int wave = tid >> 6, lane = tid & 63;
    const int wi = wave >> 1, wj = wave & 1;
    const int l15 = lane & 15, quad = lane >> 4;

    // stage B panel: coalesced 16B chunks, XOR-swizzled LDS placement
    #pragma unroll
    for (int i = 0; i < 8; ++i) {
        const int L   = i * 256 + tid;           // chunk idx [0,2048)
        const int row = L >> 4, ch = L & 15;
        const int dst = row * ZD + (((ch ^ (row & 15)) << 3));
        *(uint4*)(Bpan + dst) = ((const uint4*)(zb + (size_t)j0 * ZD))[L];
    }

    // A fragment bases + kc=0 prefetch (independent of LDS -> overlaps barrier)
    const unsigned short* abase[4];
    #pragma unroll
    for (int it = 0; it < 4; ++it)
        abase[it] = zb + (size_t)(i0 + wi * 64 + it * 16 + l15) * ZD + quad * 8;

    bf16x8 af[2][4];
    #pragma unroll
    for (int it = 0; it < 4; ++it)
        af[0][it] = *(const bf16x8*)(abase[it]);

    __syncthreads();

    f32x4 accv[4][4];
    #pragma unroll
    for (int a = 0; a < 4; ++a)
        #pragma unroll
        for (int b = 0; b < 4; ++b)
            accv[a][b] = (f32x4){0.f, 0.f, 0.f, 0.f};

    #pragma unroll
    for (int kc = 0; kc < 4; ++kc) {
        if (kc < 3) {
            #pragma unroll
            for (int it = 0; it < 4; ++it)
                af[(kc + 1) & 1][it] =
                    *(const bf16x8*)(abase[it] + (kc + 1) * 32);
        }
        bf16x8 bfr[4];
        #pragma unroll
        for (int jt = 0; jt < 4; ++jt) {
            const int row = wj * 64 + jt * 16 + l15;
            const int ch  = (quad + 4 * kc) ^ l15;
            bfr[jt] = *(const bf16x8*)(Bpan + row * ZD + (ch << 3));
        }
        #pragma unroll
        for (int it = 0; it < 4; ++it)
            #pragma unroll
            for (int jt = 0; jt < 4; ++jt)
                accv[it][jt] = __builtin_amdgcn_mfma_f32_16x16x32_bf16(
                    af[kc & 1][it], bfr[jt], accv[it][jt], 0, 0, 0);
    }

    // ---- fast epilogue: wave-max of dots vs conservative d2 lower bound ----
    float m = -1e30f;
    #pragma unroll
    for (int it = 0; it < 4; ++it)
        #pragma unroll
        for (int jt = 0; jt < 4; ++jt) {
            const f32x4 v = accv[it][jt];
            m = fmaxf(m, fmaxf(fmaxf(v[0], v[1]), fmaxf(v[2], v[3])));
        }
    #pragma unroll
    for (int off = 1; off < 64; off <<= 1)
        m = fmaxf(m, __shfl_xor(m, off, 64));

    const int gA = ti * 2 + wi, gB = tj * 2 + wj;
    const float bound = sqmin[gA] + sqmin[gB] - 2.0f * m;

    if (bound < D2_TRIG) {   // wave-uniform; fires for diag quadrants + ~1e-3
        int cnt[4] = {0, 0, 0, 0};
        for (int b = 0; b < nPrep; ++b) {
            cnt[0] += counts4[b * 4 + 0];
            cnt[1] += counts4[b * 4 + 1];
            cnt[2] += counts4[b * 4 + 2];
            cnt[3] += counts4[b * 4 + 3];
        }
        float p[4];
        #pragma unroll
        for (int cl = 0; cl < 4; ++cl) p[cl] = (float)cnt[cl] * invN;
        const float sump2 = p[0]*p[0] + p[1]*p[1] + p[2]*p[2] + p[3]*p[3];

        const int ibase = i0 + wi * 64, jbase = j0 + wj * 64;
        float sqj[4];
        #pragma unroll
        for (int jt = 0; jt < 4; ++jt) sqj[jt] = sq[jbase + jt * 16 + l15];

        float local = 0.f;
        #pragma unroll
        for (int it = 0; it < 4; ++it) {
            #pragma unroll
            for (int r = 0; r < 4; ++r) {
                const int i = ibase + it * 16 + quad * 4 + r;  // C/D row
                const float sqi = sq[i];
                #pragma unroll
                for (int jt = 0; jt < 4; ++jt) {
                    const int j = jbase + jt * 16 + l15;       // C/D col
                    float d2 = sqi + sqj[jt] - 2.0f * accv[it][jt][r];
                    d2 = fmaxf(d2, 0.0f);
                    if (d2 < D2_CUT && i != j) {
                        const int si = s[i], sj = s[j];
                        const float w = (si == sj ? 1.0f : 0.0f)
                                      - p[si] - p[sj] + sump2;
                        local += w * __expf(-0.5f * d2);
                    }
                }
            }
        }
        if (ti < tj) local *= 2.0f;

        #pragma unroll
        for (int off = 32; off > 0; off >>= 1)
            local += __shfl_down(local, off, 64);
        if (lane == 0 && local != 0.0f)
            atomicAdd(acc, local);
    }

    // ---- last-block finalize (replaces separate kernel + memset) ----
    __syncthreads();            // all waves' acc atomics issued & drained
    if (tid == 0) {
        __threadfence();
        if (atomicAdd(done, 1u) == (unsigned)gridDim.x - 1u) {
            float a = atomicAdd(acc, 0.0f);   // coherent read
            double c2 = 0.0;
            for (int cl = 0; cl < 4; ++cl) {
                long long cc = 0;
                for (int b = 0; b < nPrep; ++b) cc += counts4[b * 4 + cl];
                c2 += (double)cc * (double)cc;
            }
            double n     = (double)N;
            double diag  = n - c2 / n;           // K_z[i,i] = 1 analytically
            double total = ((double)a + diag) * (1.0 - exp(-1.0));
            out[0] = (float)(total / ((double)norm[0] * n * n));
        }
    }
}

extern "C" void kernel_launch(void* const* d_in, const int* in_sizes, int n_in,
                              void* d_out, int out_size, void* d_ws, size_t ws_size,
                              hipStream_t stream)
{
    const float* z    = (const float*)d_in[0];
    const int*   s    = (const int*)d_in[1];
    const float* norm = (const float*)d_in[2];
    float* out = (float*)d_out;

    const int N = in_sizes[1];       // 8192
    const int T = N / BT;            // 64
    const int nPrep = N / 64;        // 128

    char* ws = (char*)d_ws;
    float*        acc     = (float*)ws;                      // @0
    unsigned int* done    = (unsigned int*)(ws + 8);         // @8
    int*          counts4 = (int*)(ws + 64);                 // 128*4 ints
    float*        sq      = (float*)(ws + 64 + 2048);        // N floats
    float*        sqmin   = (float*)(ws + 64 + 2048 + (size_t)N * 4);
    unsigned short* zb    = (unsigned short*)(ws + 64 + 2048 + (size_t)N * 4
                                              + (size_t)nPrep * 4);  // 16B-aligned

    dep_prep<<<nPrep, 256, 0, stream>>>(z, s, sq, sqmin, zb, counts4, acc, done);

    const int nblocks = T * (T + 1) / 2;   // 2080
    dep_pair<<<nblocks, 256, 0, stream>>>(zb, sq, sqmin, s, counts4, nPrep,
                                          acc, done, norm, out,
                                          T, N, 1.0f / (float)N);
}

// Round 4
// 113.641 us; speedup vs baseline: 1.2500x; 1.2500x over previous
//
#include <hip/hip_runtime.h>
#include <hip/hip_bf16.h>

typedef short bf16x8 __attribute__((ext_vector_type(8)));
typedef float f32x4  __attribute__((ext_vector_type(4)));

#define ZD      128      // feature dim
#define BT      128      // block tile (128x128, 64x64 per wave)
#define D2_CUT  60.0f    // exact-path cutoff: exp(-30)~9e-14
#define D2_TRIG 62.0f    // conservative trigger (margin > any bf16 dot err)

__device__ __forceinline__ unsigned short f2bf(float x) {
    unsigned u = __float_as_uint(x);
    u = (u + 0x7FFFu + ((u >> 16) & 1u)) >> 16;
    return (unsigned short)u;
}

// triangle map: tile index t -> (ti <= tj), T x T grid, row-major triangle
__device__ __forceinline__ void trimap(int t, int T, int& ti, int& tj) {
    #define TRI_BASE(x) ((x) * T - ((x) * ((x) - 1)) / 2)
    double disc = (2.0 * T + 1.0) * (2.0 * T + 1.0) - 8.0 * (double)t;
    int x = (int)((2.0 * T + 1.0 - sqrt(disc)) * 0.5);
    if (x < 0) x = 0;
    if (x > T - 1) x = T - 1;
    while (x + 1 < T && TRI_BASE(x + 1) <= t) ++x;
    while (x > 0 && TRI_BASE(x) > t) --x;
    ti = x;
    tj = x + (t - TRI_BASE(x));
    #undef TRI_BASE
}

// lane-parallel sum of per-prep-block class counts (nPrep int4 records)
__device__ __forceinline__ void sum_counts(const int* counts4, int nPrep,
                                           int lane, int cnt[4]) {
    int c0 = 0, c1 = 0, c2 = 0, c3 = 0;
    for (int b = lane; b < nPrep; b += 64) {
        const int* p = counts4 + b * 4;
        c0 += p[0]; c1 += p[1]; c2 += p[2]; c3 += p[3];
    }
    #pragma unroll
    for (int off = 1; off < 64; off <<= 1) {
        c0 += __shfl_xor(c0, off, 64);
        c1 += __shfl_xor(c1, off, 64);
        c2 += __shfl_xor(c2, off, 64);
        c3 += __shfl_xor(c3, off, 64);
    }
    cnt[0] = c0; cnt[1] = c1; cnt[2] = c2; cnt[3] = c3;
}

// ---------------------------------------------------------------------------
// Kernel A: ||z_i||^2, per-64-row min, z->bf16, per-block class counts
// (plain stores -> no zero-init, no atomics). Block 0 zeroes acc.
// ---------------------------------------------------------------------------
__global__ __launch_bounds__(256) void dep_prep(
    const float* __restrict__ z, const int* __restrict__ s,
    float* __restrict__ sq, float* __restrict__ sqmin,
    unsigned short* __restrict__ zb, int* __restrict__ counts4,
    float* __restrict__ acc)
{
    __shared__ float part[64][33];
    const int tid  = threadIdx.x;
    const int wave = tid >> 6, lane = tid & 63;
    const int half = lane >> 5, c = lane & 31;
    const int r0   = blockIdx.x * 64;

    if (blockIdx.x == 0 && tid == 192) *acc = 0.0f;

    if (wave == 0) {
        int sv = s[r0 + lane];
        #pragma unroll
        for (int cl = 0; cl < 4; ++cl) {
            unsigned long long m = __ballot(sv == cl);
            if (lane == 0) counts4[blockIdx.x * 4 + cl] = __popcll(m);
        }
    }

    #pragma unroll
    for (int i = 0; i < 8; ++i) {
        const int rloc = wave * 16 + i * 2 + half;
        const int r    = r0 + rloc;
        float4 v = ((const float4*)z)[r * 32 + c];
        ushort4 u;
        u.x = f2bf(v.x); u.y = f2bf(v.y); u.z = f2bf(v.z); u.w = f2bf(v.w);
        ((ushort4*)zb)[r * 32 + c] = u;
        part[rloc][c] = v.x*v.x + v.y*v.y + v.z*v.z + v.w*v.w;
    }
    __syncthreads();

    if (wave == 0) {
        float sum = 0.f;
        #pragma unroll
        for (int k = 0; k < 32; ++k) sum += part[lane][k];   // conflict-free
        sq[r0 + lane] = sum;
        float mn = sum;
        #pragma unroll
        for (int off = 1; off < 64; off <<= 1)
            mn = fminf(mn, __shfl_xor(mn, off, 64));
        if (lane == 0) sqmin[blockIdx.x] = mn;
    }
}

// ---------------------------------------------------------------------------
// Kernel B: persistent — 512 blocks grid-stride over 2080 upper-triangle
// 128x128 tiles. Per tile: A+B panels in 64KB XOR-swizzled LDS (0-conflict
// pattern, verified R2); NEXT tile's panels are register-prefetched during
// the current tile's MFMA phase (hides L2 staging latency without extra
// LDS). Epilogue: conservative d2 bound -> exact path only when it fires.
// NO device-scope fences / same-address tickets (R3's 84us wall).
// ---------------------------------------------------------------------------
__global__ __launch_bounds__(256, 2) void dep_pair(
    const unsigned short* __restrict__ zb, const float* __restrict__ sq,
    const float* __restrict__ sqmin, const int* __restrict__ s,
    const int* __restrict__ counts4, int nPrep,
    float* __restrict__ acc, int T, float invN)
{
    __shared__ unsigned short Apan[BT * ZD];   // 32KB
    __shared__ unsigned short Bpan[BT * ZD];   // 32KB

    const int tid  = threadIdx.x;
    const int wave = tid >> 6, lane = tid & 63;
    const int wi = wave >> 1, wj = wave & 1;
    const int l15 = lane & 15, quad = lane >> 4;
    const int NT = T * (T + 1) / 2;

    int t = blockIdx.x;
    if (t >= NT) return;

    int ti, tj;
    trimap(t, T, ti, tj);

    // prologue: stage first tile's panels into registers
    uint4 ra[8], rb[8];
    {
        const uint4* pa = (const uint4*)(zb + (size_t)ti * BT * ZD);
        const uint4* pb = (const uint4*)(zb + (size_t)tj * BT * ZD);
        #pragma unroll
        for (int i = 0; i < 8; ++i) {
            ra[i] = pa[i * 256 + tid];
            rb[i] = pb[i * 256 + tid];
        }
    }

    while (t < NT) {
        const int cti = ti, ctj = tj;
        const int i0 = cti * BT, j0 = ctj * BT;

        // registers -> LDS (16B chunks, XOR swizzle: chunk ^= row&15)
        #pragma unroll
        for (int i = 0; i < 8; ++i) {
            const int L   = i * 256 + tid;
            const int row = L >> 4, ch = L & 15;
            const int dst = row * ZD + (((ch ^ (row & 15))) << 3);
            *(uint4*)(Apan + dst) = ra[i];
            *(uint4*)(Bpan + dst) = rb[i];
        }
        __syncthreads();

        // register-prefetch next tile's panels (overlaps MFMA phase below)
        const int tn = t + gridDim.x;
        if (tn < NT) {
            trimap(tn, T, ti, tj);
            const uint4* pa = (const uint4*)(zb + (size_t)ti * BT * ZD);
            const uint4* pb = (const uint4*)(zb + (size_t)tj * BT * ZD);
            #pragma unroll
            for (int i = 0; i < 8; ++i) {
                ra[i] = pa[i * 256 + tid];
                rb[i] = pb[i * 256 + tid];
            }
        }

        // ---- MFMA phase: 64x64 quadrant per wave ----
        f32x4 accv[4][4];
        #pragma unroll
        for (int a = 0; a < 4; ++a)
            #pragma unroll
            for (int b = 0; b < 4; ++b)
                accv[a][b] = (f32x4){0.f, 0.f, 0.f, 0.f};

        #pragma unroll
        for (int kc = 0; kc < 4; ++kc) {
            bf16x8 af[4], bfr[4];
            const int ch = (quad + 4 * kc) ^ l15;    // row&15 == l15
            #pragma unroll
            for (int it = 0; it < 4; ++it) {
                const int row = wi * 64 + it * 16 + l15;
                af[it] = *(const bf16x8*)(Apan + row * ZD + (ch << 3));
            }
            #pragma unroll
            for (int jt = 0; jt < 4; ++jt) {
                const int row = wj * 64 + jt * 16 + l15;
                bfr[jt] = *(const bf16x8*)(Bpan + row * ZD + (ch << 3));
            }
            #pragma unroll
            for (int it = 0; it < 4; ++it)
                #pragma unroll
                for (int jt = 0; jt < 4; ++jt)
                    accv[it][jt] = __builtin_amdgcn_mfma_f32_16x16x32_bf16(
                        af[it], bfr[jt], accv[it][jt], 0, 0, 0);
        }

        // ---- fast epilogue: wave-max vs conservative d2 lower bound ----
        float m = -1e30f;
        #pragma unroll
        for (int it = 0; it < 4; ++it)
            #pragma unroll
            for (int jt = 0; jt < 4; ++jt) {
                const f32x4 v = accv[it][jt];
                m = fmaxf(m, fmaxf(fmaxf(v[0], v[1]), fmaxf(v[2], v[3])));
            }
        #pragma unroll
        for (int off = 1; off < 64; off <<= 1)
            m = fmaxf(m, __shfl_xor(m, off, 64));

        const float bound = sqmin[cti * 2 + wi] + sqmin[ctj * 2 + wj] - 2.0f * m;

        if (bound < D2_TRIG) {   // wave-uniform; diag quadrants + ~1e-3 of rest
            int cnt[4];
            sum_counts(counts4, nPrep, lane, cnt);
            float p[4];
            #pragma unroll
            for (int cl = 0; cl < 4; ++cl) p[cl] = (float)cnt[cl] * invN;
            const float sump2 = p[0]*p[0] + p[1]*p[1] + p[2]*p[2] + p[3]*p[3];

            const int ibase = i0 + wi * 64, jbase = j0 + wj * 64;
            float sqj[4];
            #pragma unroll
            for (int jt = 0; jt < 4; ++jt) sqj[jt] = sq[jbase + jt * 16 + l15];

            float local = 0.f;
            #pragma unroll
            for (int it = 0; it < 4; ++it) {
                #pragma unroll
                for (int r = 0; r < 4; ++r) {
                    const int i = ibase + it * 16 + quad * 4 + r;  // C/D row
                    const float sqi = sq[i];
                    #pragma unroll
                    for (int jt = 0; jt < 4; ++jt) {
                        const int j = jbase + jt * 16 + l15;       // C/D col
                        float d2 = sqi + sqj[jt] - 2.0f * accv[it][jt][r];
                        d2 = fmaxf(d2, 0.0f);
                        if (d2 < D2_CUT && i != j) {
                            const int si = s[i], sj = s[j];
                            const float w = (si == sj ? 1.0f : 0.0f)
                                          - p[si] - p[sj] + sump2;
                            local += w * __expf(-0.5f * d2);
                        }
                    }
                }
            }
            if (cti < ctj) local *= 2.0f;   // off-diag tiles: both orders

            #pragma unroll
            for (int off = 32; off > 0; off >>= 1)
                local += __shfl_down(local, off, 64);
            if (lane == 0 && local != 0.0f)
                atomicAdd(acc, local);
        }

        __syncthreads();    // LDS reuse guard before next iteration's writes
        t = tn;
    }
}

// ---------------------------------------------------------------------------
// Kernel C: analytic diagonal (K_z[i,i]=1) + scaling. Kernel boundary
// provides coherence with pair's atomics — no fences needed.
// ---------------------------------------------------------------------------
__global__ __launch_bounds__(64) void dep_finalize(
    const float* __restrict__ acc, const int* __restrict__ counts4, int nPrep,
    const float* __restrict__ norm, float* __restrict__ out, int N)
{
    const int lane = threadIdx.x & 63;
    int cnt[4];
    sum_counts(counts4, nPrep, lane, cnt);
    if (lane == 0) {
        double n  = (double)N;
        double c2 = 0.0;
        for (int cl = 0; cl < 4; ++cl)
            c2 += (double)cnt[cl] * (double)cnt[cl];
        double diag  = n - c2 / n;
        double total = ((double)acc[0] + diag) * (1.0 - exp(-1.0));
        out[0] = (float)(total / ((double)norm[0] * n * n));
    }
}

extern "C" void kernel_launch(void* const* d_in, const int* in_sizes, int n_in,
                              void* d_out, int out_size, void* d_ws, size_t ws_size,
                              hipStream_t stream)
{
    const float* z    = (const float*)d_in[0];
    const int*   s    = (const int*)d_in[1];
    const float* norm = (const float*)d_in[2];
    float* out = (float*)d_out;

    const int N = in_sizes[1];       // 8192
    const int T = N / BT;            // 64
    const int nPrep = N / 64;        // 128

    char* ws = (char*)d_ws;
    float*        acc     = (float*)ws;                      // @0
    int*          counts4 = (int*)(ws + 64);                 // nPrep*4 ints
    float*        sq      = (float*)(ws + 64 + 2048);        // N floats
    float*        sqmin   = (float*)(ws + 64 + 2048 + (size_t)N * 4);
    unsigned short* zb    = (unsigned short*)(ws + 64 + 2048 + (size_t)N * 4
                                              + (size_t)nPrep * 4);  // 16B-aligned

    dep_prep<<<nPrep, 256, 0, stream>>>(z, s, sq, sqmin, zb, counts4, acc);
    dep_pair<<<512, 256, 0, stream>>>(zb, sq, sqmin, s, counts4, nPrep,
                                      acc, T, 1.0f / (float)N);
    dep_finalize<<<1, 64, 0, stream>>>(acc, counts4, nPrep, norm, out, N);
}

// Round 5
// 84.797 us; speedup vs baseline: 1.6752x; 1.3402x over previous
//
#include <hip/hip_runtime.h>
#include <hip/hip_bf16.h>

typedef short bf16x8 __attribute__((ext_vector_type(8)));
typedef float f32x4  __attribute__((ext_vector_type(4)));

#define ZD      128      // feature dim
#define BT      128      // block tile (128x128, 64x64 per wave)
#define D2_CUT  60.0f    // exact-path cutoff: exp(-30)~9e-14
#define D2_TRIG 62.0f    // conservative trigger (margin > any bf16 dot err)

__device__ __forceinline__ unsigned short f2bf(float x) {
    unsigned u = __float_as_uint(x);
    u = (u + 0x7FFFu + ((u >> 16) & 1u)) >> 16;
    return (unsigned short)u;
}

// ---------------------------------------------------------------------------
// Kernel A: ||z_i||^2, per-64-row-group min, z->bf16. Block 0's wave 2
// additionally computes class counts over ALL of s, the analytic diagonal
// term, and pre-initializes out[0] = diag*scale (so pair's atomics can add
// straight into out -> no finalize kernel, no memset node).
// ---------------------------------------------------------------------------
__global__ __launch_bounds__(256) void dep_prep(
    const float* __restrict__ z, const int* __restrict__ s,
    float* __restrict__ sq, float* __restrict__ sqmin,
    unsigned short* __restrict__ zb, float* __restrict__ pvals,
    const float* __restrict__ norm, float* __restrict__ out, int N)
{
    __shared__ float part[64][33];
    const int tid  = threadIdx.x;
    const int wave = tid >> 6, lane = tid & 63;
    const int half = lane >> 5, c = lane & 31;
    const int r0   = blockIdx.x * 64;

    if (blockIdx.x == 0 && wave == 2) {
        // class counts over all N samples: 32 int4 loads per lane
        int c0 = 0, c1 = 0, c2 = 0, c3 = 0;
        for (int it = lane; it < N / 4; it += 64) {
            int4 v = ((const int4*)s)[it];
            c0 += (v.x == 0) + (v.y == 0) + (v.z == 0) + (v.w == 0);
            c1 += (v.x == 1) + (v.y == 1) + (v.z == 1) + (v.w == 1);
            c2 += (v.x == 2) + (v.y == 2) + (v.z == 2) + (v.w == 2);
            c3 += (v.x == 3) + (v.y == 3) + (v.z == 3) + (v.w == 3);
        }
        #pragma unroll
        for (int off = 1; off < 64; off <<= 1) {
            c0 += __shfl_xor(c0, off, 64);
            c1 += __shfl_xor(c1, off, 64);
            c2 += __shfl_xor(c2, off, 64);
            c3 += __shfl_xor(c3, off, 64);
        }
        if (lane == 0) {
            const double n = (double)N;
            const double p0 = c0 / n, p1 = c1 / n, p2 = c2 / n, p3 = c3 / n;
            const double sump2 = p0*p0 + p1*p1 + p2*p2 + p3*p3;
            const double scale = (1.0 - exp(-1.0)) / ((double)norm[0] * n * n);
            pvals[0] = (float)p0; pvals[1] = (float)p1;
            pvals[2] = (float)p2; pvals[3] = (float)p3;
            pvals[4] = (float)sump2;
            pvals[5] = (float)scale;
            const double c2sum = (double)c0*c0 + (double)c1*c1
                               + (double)c2*c2 + (double)c3*c3;
            const double diag = n - c2sum / n;   // K_z[i,i] = 1 analytically
            out[0] = (float)(diag * scale);      // pair atomics add onto this
        }
    }

    #pragma unroll
    for (int i = 0; i < 8; ++i) {
        const int rloc = wave * 16 + i * 2 + half;
        const int r    = r0 + rloc;
        float4 v = ((const float4*)z)[r * 32 + c];
        ushort4 u;
        u.x = f2bf(v.x); u.y = f2bf(v.y); u.z = f2bf(v.z); u.w = f2bf(v.w);
        ((ushort4*)zb)[r * 32 + c] = u;
        part[rloc][c] = v.x*v.x + v.y*v.y + v.z*v.z + v.w*v.w;
    }
    __syncthreads();

    if (wave == 0) {
        float sum = 0.f;
        #pragma unroll
        for (int k = 0; k < 32; ++k) sum += part[lane][k];   // conflict-free
        sq[r0 + lane] = sum;
        float mn = sum;
        #pragma unroll
        for (int off = 1; off < 64; off <<= 1)
            mn = fminf(mn, __shfl_xor(mn, off, 64));
        if (lane == 0) sqmin[blockIdx.x] = mn;
    }
}

// ---------------------------------------------------------------------------
// Kernel B: one block per 128x128 upper-triangle tile (2080 blocks) — the
// R2-proven body. A+B panels staged via reg->LDS inside one unrolled loop
// (NO persistent prefetch live across the MFMA phase: that spilled 131MB
// to scratch in R4). XOR-swizzled LDS (0 bank conflicts, verified).
// Epilogue: conservative d2 bound; exact slow path (rare) adds
// local*scale directly onto out[0], which prep pre-set to diag*scale.
// ---------------------------------------------------------------------------
__global__ __launch_bounds__(256, 2) void dep_pair(
    const unsigned short* __restrict__ zb, const float* __restrict__ sq,
    const float* __restrict__ sqmin, const int* __restrict__ s,
    const float* __restrict__ pvals, float* __restrict__ out, int T)
{
    __shared__ unsigned short Apan[BT * ZD];   // 32KB
    __shared__ unsigned short Bpan[BT * ZD];   // 32KB

    const int tid = threadIdx.x;

    // block-uniform triangle map t -> (ti <= tj)
    const int t = blockIdx.x;
    #define TRI_BASE(x) ((x) * T - ((x) * ((x) - 1)) / 2)
    double disc = (2.0 * T + 1.0) * (2.0 * T + 1.0) - 8.0 * (double)t;
    int ti = (int)((2.0 * T + 1.0 - sqrt(disc)) * 0.5);
    if (ti < 0) ti = 0;
    if (ti > T - 1) ti = T - 1;
    while (ti + 1 < T && TRI_BASE(ti + 1) <= t) ++ti;
    while (ti > 0 && TRI_BASE(ti) > t) --ti;
    const int tj = ti + (t - TRI_BASE(ti));
    #undef TRI_BASE

    const int i0 = ti * BT, j0 = tj * BT;

    // stage both panels: coalesced 16B chunks, XOR-swizzled LDS placement
    #pragma unroll
    for (int i = 0; i < 8; ++i) {
        const int L   = i * 256 + tid;           // chunk idx [0,2048)
        const int row = L >> 4, ch = L & 15;
        const int dst = row * ZD + (((ch ^ (row & 15)) << 3));
        uint4 a = ((const uint4*)(zb + (size_t)i0 * ZD))[L];
        uint4 b = ((const uint4*)(zb + (size_t)j0 * ZD))[L];
        *(uint4*)(Apan + dst) = a;
        *(uint4*)(Bpan + dst) = b;
    }
    __syncthreads();

    const int wave = tid >> 6, lane = tid & 63;
    const int wi = wave >> 1, wj = wave & 1;
    const int l15 = lane & 15, quad = lane >> 4;

    f32x4 accv[4][4];
    #pragma unroll
    for (int a = 0; a < 4; ++a)
        #pragma unroll
        for (int b = 0; b < 4; ++b)
            accv[a][b] = (f32x4){0.f, 0.f, 0.f, 0.f};

    #pragma unroll
    for (int kc = 0; kc < 4; ++kc) {
        bf16x8 af[4], bfr[4];
        const int ch = (quad + 4 * kc) ^ l15;    // row&15 == l15
        #pragma unroll
        for (int it = 0; it < 4; ++it) {
            const int row = wi * 64 + it * 16 + l15;
            af[it] = *(const bf16x8*)(Apan + row * ZD + (ch << 3));
        }
        #pragma unroll
        for (int jt = 0; jt < 4; ++jt) {
            const int row = wj * 64 + jt * 16 + l15;
            bfr[jt] = *(const bf16x8*)(Bpan + row * ZD + (ch << 3));
        }
        #pragma unroll
        for (int it = 0; it < 4; ++it)
            #pragma unroll
            for (int jt = 0; jt < 4; ++jt)
                accv[it][jt] = __builtin_amdgcn_mfma_f32_16x16x32_bf16(
                    af[it], bfr[jt], accv[it][jt], 0, 0, 0);
    }

    // ---- fast epilogue: wave-max of dots vs conservative d2 lower bound ----
    float m = -1e30f;
    #pragma unroll
    for (int it = 0; it < 4; ++it)
        #pragma unroll
        for (int jt = 0; jt < 4; ++jt) {
            const f32x4 v = accv[it][jt];
            m = fmaxf(m, fmaxf(fmaxf(v[0], v[1]), fmaxf(v[2], v[3])));
        }
    #pragma unroll
    for (int off = 1; off < 64; off <<= 1)
        m = fmaxf(m, __shfl_xor(m, off, 64));

    const float bound = sqmin[ti * 2 + wi] + sqmin[tj * 2 + wj] - 2.0f * m;

    if (bound < D2_TRIG) {   // wave-uniform; diag quadrants + ~1e-3 of rest
        const float p0 = pvals[0], p1 = pvals[1],
                    p2 = pvals[2], p3 = pvals[3];
        const float sump2 = pvals[4], scale = pvals[5];
        const float p[4] = {p0, p1, p2, p3};

        const int ibase = i0 + wi * 64, jbase = j0 + wj * 64;
        float sqj[4];
        #pragma unroll
        for (int jt = 0; jt < 4; ++jt) sqj[jt] = sq[jbase + jt * 16 + l15];

        float local = 0.f;
        #pragma unroll
        for (int it = 0; it < 4; ++it) {
            #pragma unroll
            for (int r = 0; r < 4; ++r) {
                const int i = ibase + it * 16 + quad * 4 + r;  // C/D row
                const float sqi = sq[i];
                #pragma unroll
                for (int jt = 0; jt < 4; ++jt) {
                    const int j = jbase + jt * 16 + l15;       // C/D col
                    float d2 = sqi + sqj[jt] - 2.0f * accv[it][jt][r];
                    d2 = fmaxf(d2, 0.0f);
                    if (d2 < D2_CUT && i != j) {
                        const int si = s[i], sj = s[j];
                        const float w = (si == sj ? 1.0f : 0.0f)
                                      - p[si] - p[sj] + sump2;
                        local += w * __expf(-0.5f * d2);
                    }
                }
            }
        }
        if (ti < tj) local *= 2.0f;   // off-diag tiles count both orders

        #pragma unroll
        for (int off = 32; off > 0; off >>= 1)
            local += __shfl_down(local, off, 64);
        if (lane == 0 && local != 0.0f)
            atomicAdd(out, local * scale);
    }
}

extern "C" void kernel_launch(void* const* d_in, const int* in_sizes, int n_in,
                              void* d_out, int out_size, void* d_ws, size_t ws_size,
                              hipStream_t stream)
{
    const float* z    = (const float*)d_in[0];
    const int*   s    = (const int*)d_in[1];
    const float* norm = (const float*)d_in[2];
    float* out = (float*)d_out;

    const int N = in_sizes[1];       // 8192
    const int T = N / BT;            // 64
    const int nPrep = N / 64;        // 128

    char* ws = (char*)d_ws;
    float*          pvals = (float*)ws;                       // 6 floats @0
    float*          sq    = (float*)(ws + 64);                // N floats
    float*          sqmin = (float*)(ws + 64 + (size_t)N * 4);
    unsigned short* zb    = (unsigned short*)(ws + 64 + (size_t)N * 4
                                              + (size_t)nPrep * 4 + 48);

    dep_prep<<<nPrep, 256, 0, stream>>>(z, s, sq, sqmin, zb, pvals,
                                        norm, out, N);
    const int nblocks = T * (T + 1) / 2;   // 2080
    dep_pair<<<nblocks, 256, 0, stream>>>(zb, sq, sqmin, s, pvals, out, T);
}

// Round 6
// 82.299 us; speedup vs baseline: 1.7260x; 1.0303x over previous
//
#include <hip/hip_runtime.h>
#include <hip/hip_bf16.h>

typedef short bf16x8 __attribute__((ext_vector_type(8)));
typedef float f32x4  __attribute__((ext_vector_type(4)));

#define ZD      128      // feature dim
#define BT      128      // block tile (128x128, 64x64 per wave)
#define D2_CUT  60.0f    // exact-path cutoff: exp(-30)~9e-14
#define D2_TRIG 62.0f    // conservative trigger (margin > any bf16 dot err)

__device__ __forceinline__ unsigned short f2bf(float x) {
    unsigned u = __float_as_uint(x);
    u = (u + 0x7FFFu + ((u >> 16) & 1u)) >> 16;
    return (unsigned short)u;
}

// async global->LDS DMA, 16B per lane; LDS dest = wave-uniform base + lane*16
__device__ __forceinline__ void async_copy16(const unsigned short* g,
                                             unsigned short* l) {
    __builtin_amdgcn_global_load_lds(
        (const __attribute__((address_space(1))) unsigned int*)g,
        (__attribute__((address_space(3))) unsigned int*)l,
        16, 0, 0);
}

// ---------------------------------------------------------------------------
// Kernel A: 256 blocks x 32 rows. ||z_i||^2, per-32-row min, z->bf16.
// Block 0 / wave 2 additionally: class counts over all s, analytic diagonal,
// out[0] = diag*scale (pair atomics then add onto out -> 2-node graph).
// ---------------------------------------------------------------------------
__global__ __launch_bounds__(256) void dep_prep(
    const float* __restrict__ z, const int* __restrict__ s,
    float* __restrict__ sq, float* __restrict__ sqmin,
    unsigned short* __restrict__ zb, float* __restrict__ pvals,
    const float* __restrict__ norm, float* __restrict__ out, int N)
{
    __shared__ float part[32][33];
    const int tid  = threadIdx.x;
    const int wave = tid >> 6, lane = tid & 63;
    const int half = lane >> 5, c = lane & 31;
    const int r0   = blockIdx.x * 32;

    if (blockIdx.x == 0 && wave == 2) {
        int c0 = 0, c1 = 0, c2 = 0, c3 = 0;
        for (int it = lane; it < N / 4; it += 64) {
            int4 v = ((const int4*)s)[it];
            c0 += (v.x == 0) + (v.y == 0) + (v.z == 0) + (v.w == 0);
            c1 += (v.x == 1) + (v.y == 1) + (v.z == 1) + (v.w == 1);
            c2 += (v.x == 2) + (v.y == 2) + (v.z == 2) + (v.w == 2);
            c3 += (v.x == 3) + (v.y == 3) + (v.z == 3) + (v.w == 3);
        }
        #pragma unroll
        for (int off = 1; off < 64; off <<= 1) {
            c0 += __shfl_xor(c0, off, 64);
            c1 += __shfl_xor(c1, off, 64);
            c2 += __shfl_xor(c2, off, 64);
            c3 += __shfl_xor(c3, off, 64);
        }
        if (lane == 0) {
            const double n = (double)N;
            const double p0 = c0 / n, p1 = c1 / n, p2 = c2 / n, p3 = c3 / n;
            const double sump2 = p0*p0 + p1*p1 + p2*p2 + p3*p3;
            const double scale = (1.0 - exp(-1.0)) / ((double)norm[0] * n * n);
            pvals[0] = (float)p0; pvals[1] = (float)p1;
            pvals[2] = (float)p2; pvals[3] = (float)p3;
            pvals[4] = (float)sump2;
            pvals[5] = (float)scale;
            const double c2sum = (double)c0*c0 + (double)c1*c1
                               + (double)c2*c2 + (double)c3*c3;
            const double diag = n - c2sum / n;   // K_z[i,i] = 1 analytically
            out[0] = (float)(diag * scale);
        }
    }

    #pragma unroll
    for (int i = 0; i < 4; ++i) {
        const int rloc = wave * 8 + i * 2 + half;
        const int r    = r0 + rloc;
        float4 v = ((const float4*)z)[r * 32 + c];
        ushort4 u;
        u.x = f2bf(v.x); u.y = f2bf(v.y); u.z = f2bf(v.z); u.w = f2bf(v.w);
        ((ushort4*)zb)[r * 32 + c] = u;
        part[rloc][c] = v.x*v.x + v.y*v.y + v.z*v.z + v.w*v.w;
    }
    __syncthreads();

    if (wave == 0 && lane < 32) {
        float sum = 0.f;
        #pragma unroll
        for (int k = 0; k < 32; ++k) sum += part[lane][k];   // conflict-free
        sq[r0 + lane] = sum;
        float mn = sum;
        #pragma unroll
        for (int off = 1; off < 32; off <<= 1)               // lanes 0..31 only
            mn = fminf(mn, __shfl_xor(mn, off, 64));
        if (lane == 0) sqmin[blockIdx.x] = mn;
    }
}

// ---------------------------------------------------------------------------
// Kernel B: one block per 128x128 upper-triangle tile (2080 blocks).
// Panels staged via global_load_lds (async DMA, no VGPR round-trip).
// XOR swizzle preserved by permuting the PER-LANE GLOBAL address
// (gch = c ^ (row&15)) -> LDS layout identical to the R2/R5-verified
// 0-conflict pattern; DMA LDS base stays wave-uniform as required.
// Epilogue: conservative d2 bound; rare exact path adds local*scale onto
// out[0] (pre-set to diag*scale by prep).
// ---------------------------------------------------------------------------
__global__ __launch_bounds__(256, 2) void dep_pair(
    const unsigned short* __restrict__ zb, const float* __restrict__ sq,
    const float* __restrict__ sqmin, const int* __restrict__ s,
    const float* __restrict__ pvals, float* __restrict__ out, int T)
{
    __shared__ unsigned short Apan[BT * ZD];   // 32KB
    __shared__ unsigned short Bpan[BT * ZD];   // 32KB

    const int tid  = threadIdx.x;
    const int wave = tid >> 6, lane = tid & 63;

    // block-uniform triangle map t -> (ti <= tj)
    const int t = blockIdx.x;
    #define TRI_BASE(x) ((x) * T - ((x) * ((x) - 1)) / 2)
    double disc = (2.0 * T + 1.0) * (2.0 * T + 1.0) - 8.0 * (double)t;
    int ti = (int)((2.0 * T + 1.0 - sqrt(disc)) * 0.5);
    if (ti < 0) ti = 0;
    if (ti > T - 1) ti = T - 1;
    while (ti + 1 < T && TRI_BASE(ti + 1) <= t) ++ti;
    while (ti > 0 && TRI_BASE(ti) > t) --ti;
    const int tj = ti + (t - TRI_BASE(ti));
    #undef TRI_BASE

    const int i0 = ti * BT, j0 = tj * BT;

    // async stage: each wave issues 8 A + 8 B DMAs of 1KB (4 rows each)
    {
        const unsigned short* gAp = zb + (size_t)i0 * ZD;
        const unsigned short* gBp = zb + (size_t)j0 * ZD;
        const int rl  = lane >> 4;          // row within 4-row issue group
        const int c   = lane & 15;          // dest 16B-chunk within row
        #pragma unroll
        for (int k = 0; k < 8; ++k) {
            const int r0i = (wave * 8 + k) * 4;       // wave-uniform
            const int row = r0i + rl;
            const int gch = c ^ (row & 15);           // global-side swizzle
            const size_t go = (size_t)row * ZD + (gch << 3);
            async_copy16(gAp + go, Apan + r0i * ZD);  // base wave-uniform
            async_copy16(gBp + go, Bpan + r0i * ZD);
        }
    }
    __syncthreads();   // compiler emits vmcnt(0) drain; other block overlaps

    const int wi = wave >> 1, wj = wave & 1;
    const int l15 = lane & 15, quad = lane >> 4;

    f32x4 accv[4][4];
    #pragma unroll
    for (int a = 0; a < 4; ++a)
        #pragma unroll
        for (int b = 0; b < 4; ++b)
            accv[a][b] = (f32x4){0.f, 0.f, 0.f, 0.f};

    #pragma unroll
    for (int kc = 0; kc < 4; ++kc) {
        bf16x8 af[4], bfr[4];
        const int ch = (quad + 4 * kc) ^ l15;    // row&15 == l15
        #pragma unroll
        for (int it = 0; it < 4; ++it) {
            const int row = wi * 64 + it * 16 + l15;
            af[it] = *(const bf16x8*)(Apan + row * ZD + (ch << 3));
        }
        #pragma unroll
        for (int jt = 0; jt < 4; ++jt) {
            const int row = wj * 64 + jt * 16 + l15;
            bfr[jt] = *(const bf16x8*)(Bpan + row * ZD + (ch << 3));
        }
        #pragma unroll
        for (int it = 0; it < 4; ++it)
            #pragma unroll
            for (int jt = 0; jt < 4; ++jt)
                accv[it][jt] = __builtin_amdgcn_mfma_f32_16x16x32_bf16(
                    af[it], bfr[jt], accv[it][jt], 0, 0, 0);
    }

    // ---- fast epilogue: wave-max of dots vs conservative d2 lower bound ----
    float m = -1e30f;
    #pragma unroll
    for (int it = 0; it < 4; ++it)
        #pragma unroll
        for (int jt = 0; jt < 4; ++jt) {
            const f32x4 v = accv[it][jt];
            m = fmaxf(m, fmaxf(fmaxf(v[0], v[1]), fmaxf(v[2], v[3])));
        }
    #pragma unroll
    for (int off = 1; off < 64; off <<= 1)
        m = fmaxf(m, __shfl_xor(m, off, 64));

    const int gA = (i0 >> 5) + wi * 2;        // 32-row sqmin groups
    const int gB = (j0 >> 5) + wj * 2;
    const float sminA = fminf(sqmin[gA], sqmin[gA + 1]);
    const float sminB = fminf(sqmin[gB], sqmin[gB + 1]);
    const float bound = sminA + sminB - 2.0f * m;

    if (bound < D2_TRIG) {   // wave-uniform; diag quadrants + ~1e-3 of rest
        const float p0 = pvals[0], p1 = pvals[1],
                    p2 = pvals[2], p3 = pvals[3];
        const float sump2 = pvals[4], scale = pvals[5];
        const float p[4] = {p0, p1, p2, p3};

        const int ibase = i0 + wi * 64, jbase = j0 + wj * 64;
        float sqj[4];
        #pragma unroll
        for (int jt = 0; jt < 4; ++jt) sqj[jt] = sq[jbase + jt * 16 + l15];

        float local = 0.f;
        #pragma unroll
        for (int it = 0; it < 4; ++it) {
            #pragma unroll
            for (int r = 0; r < 4; ++r) {
                const int i = ibase + it * 16 + quad * 4 + r;  // C/D row
                const float sqi = sq[i];
                #pragma unroll
                for (int jt = 0; jt < 4; ++jt) {
                    const int j = jbase + jt * 16 + l15;       // C/D col
                    float d2 = sqi + sqj[jt] - 2.0f * accv[it][jt][r];
                    d2 = fmaxf(d2, 0.0f);
                    if (d2 < D2_CUT && i != j) {
                        const int si = s[i], sj = s[j];
                        const float w = (si == sj ? 1.0f : 0.0f)
                                      - p[si] - p[sj] + sump2;
                        local += w * __expf(-0.5f * d2);
                    }
                }
            }
        }
        if (ti < tj) local *= 2.0f;   // off-diag tiles count both orders

        #pragma unroll
        for (int off = 32; off > 0; off >>= 1)
            local += __shfl_down(local, off, 64);
        if (lane == 0 && local != 0.0f)
            atomicAdd(out, local * scale);
    }
}

extern "C" void kernel_launch(void* const* d_in, const int* in_sizes, int n_in,
                              void* d_out, int out_size, void* d_ws, size_t ws_size,
                              hipStream_t stream)
{
    const float* z    = (const float*)d_in[0];
    const int*   s    = (const int*)d_in[1];
    const float* norm = (const float*)d_in[2];
    float* out = (float*)d_out;

    const int N = in_sizes[1];       // 8192
    const int T = N / BT;            // 64

    char* ws = (char*)d_ws;
    float*          pvals = (float*)ws;                       // 6 floats @0
    float*          sq    = (float*)(ws + 64);                // N floats
    float*          sqmin = (float*)(ws + 64 + (size_t)N * 4);        // N/32
    unsigned short* zb    = (unsigned short*)(ws + 64 + (size_t)N * 4
                                              + (size_t)(N / 32) * 4); // 16B-aligned

    dep_prep<<<N / 32, 256, 0, stream>>>(z, s, sq, sqmin, zb, pvals,
                                         norm, out, N);
    const int nblocks = T * (T + 1) / 2;   // 2080
    dep_pair<<<nblocks, 256, 0, stream>>>(zb, sq, sqmin, s, pvals, out, T);
}